// Round 1
// baseline (515.885 us; speedup 1.0000x reference)
//
#include <hip/hip_runtime.h>

// out[b, m, p, q] = (1/SIDE^2) * sum_k vert[p,k] * hor[q,k]
//   m=0 (hf): K=64, x = {a0, b1-STRIP}, y = {b0, a1}
//     hor[q,k]  = relu(min(SIDE, (q+1)*SIDE - x_k, y_k - q*SIDE))
//     vert[p,k] = relu(min(SIDE, PY[p]+SIDE - y_k, x_k + STRIP - PY[p])), PY[p]=(511-p)*SIDE
//   m=1 (ri): K=32, x = a0, y = b0
//     hor[q,k]  = relu(min(SIDE, (q+1)*SIDE - x_k))
//     vert[p,k] = relu(min(SIDE, y_k - PY[p]))
// We normalize hor/vert by 1/SIDE so products sum directly to the final value
// (absorbs the /PIXEL_AREA), and values lie in [0,1] for bf16 accuracy.

#define P_DIM 512
#define TILE 128
#define LDS_STRIDE 72   // 64 + 8 pad shorts -> 36-word row stride, uniform bank use for b128 frag reads

constexpr float SIDEF     = (float)(1.5707963267948966 / 512.0);
constexpr float STRIPF    = (float)(1.5707963267948966);
constexpr float INV_SIDEF = (float)(512.0 / 1.5707963267948966);

typedef __attribute__((ext_vector_type(8))) short bf16x8;
typedef __attribute__((ext_vector_type(4))) float f32x4;

__device__ __forceinline__ unsigned short f2bf(float f) {
    unsigned int u = __float_as_uint(f);
    u += 0x7fffu + ((u >> 16) & 1u);   // round-to-nearest-even
    return (unsigned short)(u >> 16);
}

__global__ __launch_bounds__(256, 2)
void raster_kernel(const float* __restrict__ iv00, const float* __restrict__ iv01,
                   float* __restrict__ out)
{
    const int b  = blockIdx.z;
    const int m  = blockIdx.y;
    const int tp = (blockIdx.x >> 2) * TILE;   // p-tile origin
    const int tq = (blockIdx.x & 3) * TILE;    // q-tile origin

    __shared__ unsigned short v_s[TILE * LDS_STRIDE];  // vert, [p][k] bf16 normalized
    __shared__ unsigned short h_s[TILE * LDS_STRIDE];  // hor,  [q][k]
    __shared__ float xk[64], yk[64];

    const int tid = threadIdx.x;

    // Load the batch's intervals and build the x/y endpoint lists.
    if (tid < 32) {
        float a0 = iv00[b * 64 + 2 * tid];
        float b0 = iv00[b * 64 + 2 * tid + 1];
        if (m == 0) {
            float a1 = iv01[b * 64 + 2 * tid];
            float b1 = iv01[b * 64 + 2 * tid + 1];
            xk[tid]      = a0;            yk[tid]      = b0;
            xk[tid + 32] = b1 - STRIPF;   yk[tid + 32] = a1;
        } else {
            xk[tid] = a0;  yk[tid] = b0;
        }
    }
    __syncthreads();

    // Stage normalized bf16 hor/vert tiles into LDS.
    const int kbits = (m == 0) ? 6 : 5;
    const int K     = 1 << kbits;
    for (int i = tid; i < TILE * K; i += 256) {
        int k = i & (K - 1);
        int r = i >> kbits;
        float xv = xk[k], yv = yk[k];
        float q0 = (float)(tq + r) * SIDEF;          // PX[q]
        float py = (float)(511 - (tp + r)) * SIDEF;  // PY[p]
        float h, v;
        if (m == 0) {
            h = fminf(SIDEF, fminf(q0 + SIDEF - xv, yv - q0));
            v = fminf(SIDEF, fminf(py + SIDEF - yv, xv + STRIPF - py));
        } else {
            h = fminf(SIDEF, q0 + SIDEF - xv);
            v = fminf(SIDEF, yv - py);
        }
        h_s[r * LDS_STRIDE + k] = f2bf(fmaxf(h, 0.0f) * INV_SIDEF);
        v_s[r * LDS_STRIDE + k] = f2bf(fmaxf(v, 0.0f) * INV_SIDEF);
    }
    __syncthreads();

    const int lane = tid & 63;
    const int wave = tid >> 6;     // wave owns p-rows [wave*32, wave*32+32)
    const int col  = lane & 15;    // A row / B row / D col
    const int quad = lane >> 4;    // k-block select; D row group

    f32x4 acc[2][8];
    #pragma unroll
    for (int sp = 0; sp < 2; ++sp)
        #pragma unroll
        for (int sq = 0; sq < 8; ++sq)
            acc[sp][sq] = (f32x4){0.f, 0.f, 0.f, 0.f};

    const int nks = (m == 0) ? 2 : 1;
    for (int ks = 0; ks < nks; ++ks) {
        const int k0 = ks * 32 + quad * 8;
        bf16x8 a0 = *(const bf16x8*)&v_s[(wave * 32 +      col) * LDS_STRIDE + k0];
        bf16x8 a1 = *(const bf16x8*)&v_s[(wave * 32 + 16 + col) * LDS_STRIDE + k0];
        #pragma unroll
        for (int sq = 0; sq < 8; ++sq) {
            bf16x8 bf = *(const bf16x8*)&h_s[(sq * 16 + col) * LDS_STRIDE + k0];
            acc[0][sq] = __builtin_amdgcn_mfma_f32_16x16x32_bf16(a0, bf, acc[0][sq], 0, 0, 0);
            acc[1][sq] = __builtin_amdgcn_mfma_f32_16x16x32_bf16(a1, bf, acc[1][sq], 0, 0, 0);
        }
    }

    // Epilogue: D layout col=lane&15, row=quad*4+reg. 16 consecutive dwords
    // per quad-row per subtile -> 64B-aligned full segments.
    float* obase = out + (size_t)(b * 2 + m) * P_DIM * P_DIM;
    #pragma unroll
    for (int sp = 0; sp < 2; ++sp) {
        #pragma unroll
        for (int r = 0; r < 4; ++r) {
            int p = tp + wave * 32 + sp * 16 + quad * 4 + r;
            float* rowp = obase + (size_t)p * P_DIM + tq;
            #pragma unroll
            for (int sq = 0; sq < 8; ++sq) {
                rowp[sq * 16 + col] = acc[sp][sq][r];
            }
        }
    }
}

extern "C" void kernel_launch(void* const* d_in, const int* in_sizes, int n_in,
                              void* d_out, int out_size, void* d_ws, size_t ws_size,
                              hipStream_t stream) {
    const float* iv00 = (const float*)d_in[0];
    const float* iv01 = (const float*)d_in[1];
    float* out = (float*)d_out;
    dim3 grid(16, 2, 256);   // 4x4 tiles of 128x128, 2 matrices, 256 batches
    raster_kernel<<<grid, dim3(256), 0, stream>>>(iv00, iv01, out);
}

// Round 2
// 512.910 us; speedup vs baseline: 1.0058x; 1.0058x over previous
//
#include <hip/hip_runtime.h>

// out[b, m, p, q] = (1/SIDE^2) * sum_k vert[p,k] * hor[q,k]
//   m=0 (hf): K=64, x = {a0, b1-STRIP}, y = {b0, a1}
//     hor[q,k]  = relu(min(SIDE, (q+1)*SIDE - x_k, y_k - q*SIDE))
//     vert[p,k] = relu(min(SIDE, PY[p]+SIDE - y_k, x_k + STRIP - PY[p])), PY[p]=(511-p)*SIDE
//   m=1 (ri): K=32, x = a0, y = b0
//     hor[q,k]  = relu(min(SIDE, (q+1)*SIDE - x_k))
//     vert[p,k] = relu(min(SIDE, y_k - PY[p]))
// hor/vert normalized by 1/SIDE (absorbs /PIXEL_AREA, keeps values in [0,1] for bf16).
//
// MFMA role swap vs round 1: A = hor (q rows), B = vert (p rows), so the
// D-layout reg index (row = quad*4+reg) walks q — the contiguous output dim —
// enabling float4 (dwordx4) stores: 16 B/lane, 64 B/row-segment per instr.

#define P_DIM 512
#define TILE 128
#define LDS_STRIDE 72   // 64 + 8 pad shorts; b128 frag reads land 2-way max on banks

constexpr float SIDEF     = (float)(1.5707963267948966 / 512.0);
constexpr float STRIPF    = (float)(1.5707963267948966);
constexpr float INV_SIDEF = (float)(512.0 / 1.5707963267948966);

typedef __attribute__((ext_vector_type(8))) short bf16x8;
typedef __attribute__((ext_vector_type(4))) float f32x4;

__device__ __forceinline__ unsigned short f2bf(float f) {
    unsigned int u = __float_as_uint(f);
    u += 0x7fffu + ((u >> 16) & 1u);   // round-to-nearest-even
    return (unsigned short)(u >> 16);
}

__global__ __launch_bounds__(256, 4)
void raster_kernel(const float* __restrict__ iv00, const float* __restrict__ iv01,
                   float* __restrict__ out)
{
    const int b  = blockIdx.z;
    const int m  = blockIdx.y;
    const int tp = (blockIdx.x >> 2) * TILE;   // p-tile origin
    const int tq = (blockIdx.x & 3) * TILE;    // q-tile origin

    __shared__ unsigned short h_s[TILE * LDS_STRIDE];  // hor,  [q][k] bf16 normalized
    __shared__ unsigned short v_s[TILE * LDS_STRIDE];  // vert, [p][k]
    __shared__ float xk[64], yk[64];

    const int tid = threadIdx.x;

    // Load the batch's intervals and build the x/y endpoint lists.
    if (tid < 32) {
        float a0 = iv00[b * 64 + 2 * tid];
        float b0 = iv00[b * 64 + 2 * tid + 1];
        if (m == 0) {
            float a1 = iv01[b * 64 + 2 * tid];
            float b1 = iv01[b * 64 + 2 * tid + 1];
            xk[tid]      = a0;            yk[tid]      = b0;
            xk[tid + 32] = b1 - STRIPF;   yk[tid + 32] = a1;
        } else {
            xk[tid] = a0;  yk[tid] = b0;
        }
    }
    __syncthreads();

    // Stage normalized bf16 hor/vert tiles. Since 256 % K == 0, each thread's
    // k is fixed: hoist the k-dependent terms out of the row loop.
    const int kbits = (m == 0) ? 6 : 5;
    const int K     = 1 << kbits;
    {
        const int k     = tid & (K - 1);
        const int r0    = tid >> kbits;
        const int rstep = 256 >> kbits;
        const float xv = xk[k], yv = yk[k];
        const float h_t1 = SIDEF - xv;            // h = min(SIDE, q0 + h_t1, yv - q0)
        const float v_t1 = SIDEF - yv;            // v = min(SIDE, py + v_t1, xv + STRIP - py)
        const float v_t2 = xv + STRIPF;
        for (int r = r0; r < TILE; r += rstep) {
            float q0 = (float)(tq + r) * SIDEF;          // PX[q]
            float py = (float)(511 - (tp + r)) * SIDEF;  // PY[p]
            float h, v;
            if (m == 0) {
                h = fminf(SIDEF, fminf(q0 + h_t1, yv - q0));
                v = fminf(SIDEF, fminf(py + v_t1, v_t2 - py));
            } else {
                h = fminf(SIDEF, q0 + h_t1);
                v = fminf(SIDEF, yv - py);
            }
            h_s[r * LDS_STRIDE + k] = f2bf(fmaxf(h, 0.0f) * INV_SIDEF);
            v_s[r * LDS_STRIDE + k] = f2bf(fmaxf(v, 0.0f) * INV_SIDEF);
        }
    }
    __syncthreads();

    const int lane = tid & 63;
    const int wave = tid >> 6;     // wave owns q-rows [wave*32, wave*32+32)
    const int col  = lane & 15;    // A row (q) / B row (p) / D col (p)
    const int quad = lane >> 4;    // k-block select; D row group (q)

    f32x4 acc[2][8];               // [q-subtile][p-subtile]
    #pragma unroll
    for (int qs = 0; qs < 2; ++qs)
        #pragma unroll
        for (int ps = 0; ps < 8; ++ps)
            acc[qs][ps] = (f32x4){0.f, 0.f, 0.f, 0.f};

    const int nks = (m == 0) ? 2 : 1;
    for (int ks = 0; ks < nks; ++ks) {
        const int k0 = ks * 32 + quad * 8;
        bf16x8 a0 = *(const bf16x8*)&h_s[(wave * 32 +      col) * LDS_STRIDE + k0];
        bf16x8 a1 = *(const bf16x8*)&h_s[(wave * 32 + 16 + col) * LDS_STRIDE + k0];
        #pragma unroll
        for (int ps = 0; ps < 8; ++ps) {
            bf16x8 bf = *(const bf16x8*)&v_s[(ps * 16 + col) * LDS_STRIDE + k0];
            acc[0][ps] = __builtin_amdgcn_mfma_f32_16x16x32_bf16(a0, bf, acc[0][ps], 0, 0, 0);
            acc[1][ps] = __builtin_amdgcn_mfma_f32_16x16x32_bf16(a1, bf, acc[1][ps], 0, 0, 0);
        }
    }

    // Epilogue: D row (= quad*4+reg) walks q -> each lane's f32x4 is 4
    // consecutive q values at fixed p. float4 stores, 16 B/lane;
    // lanes of one instr cover 16 rows x 64 B contiguous segments, and the
    // qs=0/1 pair completes 128 B per row.
    float* obase = out + (size_t)(b * 2 + m) * P_DIM * P_DIM;
    const int qbase = tq + wave * 32 + quad * 4;
    #pragma unroll
    for (int ps = 0; ps < 8; ++ps) {
        int p = tp + ps * 16 + col;
        float* rowp = obase + (size_t)p * P_DIM;
        #pragma unroll
        for (int qs = 0; qs < 2; ++qs) {
            *(f32x4*)&rowp[qbase + qs * 16] = acc[qs][ps];
        }
    }
}

extern "C" void kernel_launch(void* const* d_in, const int* in_sizes, int n_in,
                              void* d_out, int out_size, void* d_ws, size_t ws_size,
                              hipStream_t stream) {
    const float* iv00 = (const float*)d_in[0];
    const float* iv01 = (const float*)d_in[1];
    float* out = (float*)d_out;
    dim3 grid(16, 2, 256);   // 4x4 tiles of 128x128, 2 matrices, 256 batches
    raster_kernel<<<grid, dim3(256), 0, stream>>>(iv00, iv01, out);
}